// Round 16
// baseline (289.112 us; speedup 1.0000x reference)
//
#include <hip/hip_runtime.h>
#include <math.h>

#define NPAIRS 195
#define NTHREADS 256
#define ROW_OUT 258                // 63 copied + 195 distances
#define WROWS 4                    // rows per WAVE-tile
#define WTILE_F (WROWS * ROW_OUT)  // 1032 floats = 4128 B per wave
#define WIN_F (WROWS * 63)         // 252 floats input per wave-tile
#define NWAVES 4                   // waves per block
#define GRID 2048                  // 8 blocks/CU on 256 CUs

typedef float f32x4 __attribute__((ext_vector_type(4)));

// ---- compile-time pair table, packed as (3i | 3j<<16) : direct col offsets ----
struct CodeTab { unsigned int c[NPAIRS]; };

constexpr CodeTab make_codes() {
    CodeTab t{};
    int n = 0;
    for (int a = 0; a < 20; ++a) {
        bool tip = (a == 4) || (a == 8) || (a == 12) || (a == 16) || (a == 19);
        int start = tip ? a + 1 : a + 2;
        for (int b = start; b < 21; ++b) {
            t.c[n] = (unsigned int)(3 * a) | ((unsigned int)(3 * b) << 16);
            ++n;
        }
    }
    return t;
}

__constant__ CodeTab CODES = make_codes();

// in : [B, 63]  (21 landmarks x (x,y,z))
// out: [B, 258] = [copy of 63 | 195 pairwise 2D distances]
//
// WAVE-AUTONOMOUS: each wave owns a private 4-row LDS tile; load->scatter->
// compute->store are wave-internal (lgkmcnt-ordered by the compiler).
// NO __syncthreads in the main loop -- waves drift & destagger freely.
__global__ __launch_bounds__(NTHREADS, 8)
void HandKineticLayer_18545668784560_kernel(const float* __restrict__ in,
                                            float* __restrict__ out,
                                            int B) {
    __shared__ __align__(16) float lds[NWAVES][WTILE_F];   // 16512 B total

    const int t = threadIdx.x;
    const int w = t >> 6;          // wave id within block
    const int l = t & 63;          // lane
    float* __restrict__ wl = &lds[w][0];

    // scatter geometry (per-lane constants), hoisted once: element g = l + 64e
    int grow[4], gcol[4];
#pragma unroll
    for (int e = 0; e < 4; ++e) {
        const int g = l + 64 * e;
        grow[e] = g / 63;
        gcol[e] = g - grow[e] * 63;
    }
    // dist geometry: quarter-wave r = l>>4 owns row r; pair p = q + 16k
    const int r = l >> 4;
    const int q = l & 15;

    const int nwt = B / WROWS;                 // full wave-tiles
    const int wt0 = blockIdx.x * NWAVES + w;

    for (int wt = wt0; wt < nwt; wt += GRID * NWAVES) {
        const float* __restrict__ ip = in + (size_t)wt * WIN_F;

        // ---- load 252 floats (3 full + 1 predicated lane-loads) ----
        const float v0 = __builtin_nontemporal_load(ip + l);
        const float v1 = __builtin_nontemporal_load(ip + l + 64);
        const float v2 = __builtin_nontemporal_load(ip + l + 128);
        const float v3 = (l < 60) ? __builtin_nontemporal_load(ip + l + 192) : 0.f;

        // ---- scatter into wave-private tile copy-cols ----
        wl[grow[0] * ROW_OUT + gcol[0]] = v0;
        wl[grow[1] * ROW_OUT + gcol[1]] = v1;
        wl[grow[2] * ROW_OUT + gcol[2]] = v2;
        if (l < 60) wl[grow[3] * ROW_OUT + gcol[3]] = v3;

        // ---- distances: row r, pairs p = q+16k, read copy-cols in place ----
        {
            float* __restrict__ row = wl + r * ROW_OUT;
#pragma unroll
            for (int k = 0; k < 13; ++k) {
                if (k < 12 || q < 3) {                 // p < 195
                    const unsigned int c = CODES.c[q + (k << 4)];
                    const int ca = (int)(c & 0xffffu); // 3*i
                    const int cb = (int)(c >> 16);     // 3*j
                    const float dx = row[ca] - row[cb];
                    const float dy = row[ca + 1] - row[cb + 1];
                    row[63 + q + (k << 4)] =
                        __builtin_amdgcn_sqrtf(dx * dx + dy * dy);
                }
            }
        }

        // ---- store the 1032-float wave-tile: 258 float4s, contiguous ----
        {
            const f32x4* __restrict__ s4 = reinterpret_cast<const f32x4*>(wl);
            f32x4* __restrict__ o4 =
                reinterpret_cast<f32x4*>(out + (size_t)wt * WTILE_F);
#pragma unroll
            for (int e = 0; e < 4; ++e) {
                const int k = l + 64 * e;              // 0..255
                __builtin_nontemporal_store(s4[k], &o4[k]);
            }
            if (l < 2) {                               // k = 256, 257
                __builtin_nontemporal_store(s4[256 + l], &o4[256 + l]);
            }
        }
        // next iteration's scatter overwrites wl -- same-wave program order,
        // compiler-inserted lgkmcnt orders it after the ds_reads above.
    }

    // ---- tail rows (B % 4 != 0): one wave, wave-local, barrier-free ----
    const int rem = B - nwt * WROWS;
    if (rem > 0 && blockIdx.x == 0 && w == 0) {
        const int rowBase = nwt * WROWS;
        for (int rr = 0; rr < rem; ++rr) {
            const size_t ib = (size_t)(rowBase + rr) * 63;
            if (l < 63) wl[l] = in[ib + l];
            float* __restrict__ op = out + (size_t)(rowBase + rr) * ROW_OUT;
            if (l < 63) op[l] = wl[l];
#pragma unroll
            for (int k = 0; k < 4; ++k) {
                const int p = l + (k << 6);
                if (p < NPAIRS) {
                    const unsigned int c = CODES.c[p];
                    const int ca = (int)(c & 0xffffu);
                    const int cb = (int)(c >> 16);
                    const float dx = wl[ca] - wl[cb];
                    const float dy = wl[ca + 1] - wl[cb + 1];
                    op[63 + p] = __builtin_amdgcn_sqrtf(dx * dx + dy * dy);
                }
            }
        }
    }
}

extern "C" void kernel_launch(void* const* d_in, const int* in_sizes, int n_in,
                              void* d_out, int out_size, void* d_ws, size_t ws_size,
                              hipStream_t stream) {
    const float* in = (const float*)d_in[0];
    float* out = (float*)d_out;
    const int B = in_sizes[0] / 63;
    hipLaunchKernelGGL(HandKineticLayer_18545668784560_kernel,
                       dim3(GRID), dim3(NTHREADS), 0, stream,
                       in, out, B);
}

// Round 17
// 256.037 us; speedup vs baseline: 1.1292x; 1.1292x over previous
//
#include <hip/hip_runtime.h>
#include <math.h>

#define ROWS 16
#define NPAIRS 195
#define NTHREADS 256
#define ROW_OUT 258            // 63 copied + 195 distances
#define TILE_F (ROWS * ROW_OUT)   // 4128 floats = 16512 B
#define IN_F (ROWS * 63)          // 1008 floats
#define GRID 2048                 // 8 blocks/CU on 256 CUs

typedef float f32x4 __attribute__((ext_vector_type(4)));

// ---- compile-time pair table, packed as (3i | 3j<<16) : direct col offsets ----
struct CodeTab { unsigned int c[NPAIRS]; };

constexpr CodeTab make_codes() {
    CodeTab t{};
    int n = 0;
    for (int a = 0; a < 20; ++a) {
        bool tip = (a == 4) || (a == 8) || (a == 12) || (a == 16) || (a == 19);
        int start = tip ? a + 1 : a + 2;
        for (int b = start; b < 21; ++b) {
            t.c[n] = (unsigned int)(3 * a) | ((unsigned int)(3 * b) << 16);
            ++n;
        }
    }
    return t;
}

__constant__ CodeTab CODES = make_codes();

// thread t<252 owns column col=t%63 of rows r0,r0+4,r0+8,r0+12 (r0=t/63).
__device__ __forceinline__ void scatter_tile(float* __restrict__ tile,
                                             const float v[4], int r0, int col) {
#pragma unroll
    for (int e = 0; e < 4; ++e) {
        tile[(r0 + 4 * e) * ROW_OUT + col] = v[e];
    }
}

// row-grouped: r = t>>4 (16 rows x 16-lane groups), pair p = q + 16k.
// landmarks read straight from the tile's copy columns (x=col 3i, y=3i+1).
__device__ __forceinline__ void compute_dists(float* __restrict__ tile, int t) {
    const int r = t >> 4;
    const int q = t & 15;
    float* __restrict__ row = tile + r * ROW_OUT;
#pragma unroll
    for (int k = 0; k < 13; ++k) {
        const int p = q + (k << 4);
        if (k < 12 || q < 3) {              // p < 195
            const unsigned int c = CODES.c[p];
            const int ca = (int)(c & 0xffffu);     // 3*i
            const int cb = (int)(c >> 16);         // 3*j
            const float ax = row[ca], ay = row[ca + 1];
            const float bx = row[cb], by = row[cb + 1];
            const float dx = ax - bx;
            const float dy = ay - by;
            row[63 + p] = __builtin_amdgcn_sqrtf(dx * dx + dy * dy);
        }
    }
}

// in : [B, 63]  (21 landmarks x (x,y,z))
// out: [B, 258] = [copy of 63 | 195 pairwise 2D distances]
__global__ __launch_bounds__(NTHREADS, 8)
void HandKineticLayer_18545668784560_kernel(const float* __restrict__ in,
                                            float* __restrict__ out,
                                            int B) {
    // SINGLE buffer, 16.5 KB -> 8 blocks/CU (wave-limited).
    __shared__ __align__(16) float tile[TILE_F];

    const int t = threadIdx.x;
    const int ntiles = B / ROWS;

    // load/copy geometry (t < 252), hoisted once
    const int r0 = t / 63;
    const int col = t - r0 * 63;

    // ---- prologue: load + scatter first tile's copy cols ----
    const int tile0 = blockIdx.x;
    if (tile0 < ntiles) {
        if (t < 252) {
            const float* __restrict__ ip = in + (size_t)tile0 * IN_F + t;
            float v[4];
#pragma unroll
            for (int e = 0; e < 4; ++e)
                v[e] = __builtin_nontemporal_load(ip + 252 * e);
            scatter_tile(tile, v, r0, col);
        }
        __syncthreads();
    }

    // ---- main loop: prefetch(k+1)->regs || compute(k); store(k); scatter(k+1) ----
    for (int tl = tile0; tl < ntiles; tl += GRID) {
        const int nxt = tl + GRID;
        float vn[4] = {0.f, 0.f, 0.f, 0.f};
        const bool have_next = (nxt < ntiles) && (t < 252);
        if (have_next) {
            const float* __restrict__ ip = in + (size_t)nxt * IN_F + t;
#pragma unroll
            for (int e = 0; e < 4; ++e)
                vn[e] = __builtin_nontemporal_load(ip + 252 * e);
        }

        compute_dists(tile, t);     // reads copy-cols, writes dist-cols
        __syncthreads();            // dists visible before store reads

        {
            const f32x4* __restrict__ tl4 =
                reinterpret_cast<const f32x4*>(&tile[0]);
            f32x4* __restrict__ o4 =
                reinterpret_cast<f32x4*>(out + (size_t)tl * TILE_F);
#pragma unroll
            for (int k = t; k < TILE_F / 4; k += NTHREADS) {
                __builtin_nontemporal_store(tl4[k], &o4[k]);
            }
        }
        __syncthreads();            // all waves done READING tile before overwrite

        if (have_next) {
            scatter_tile(tile, vn, r0, col);
        }
        __syncthreads();            // scatter visible for next compute
    }

    // ---- tail: partial tile (B % 16 != 0), one block, non-pipelined ----
    const int rem = B - ntiles * ROWS;
    if (rem > 0 && blockIdx.x == (unsigned)(ntiles % GRID)) {
        const int rowBase = ntiles * ROWS;
        const int nelem = rem * 63;
        for (int g = t; g < nelem; g += NTHREADS) {
            const float val = in[(size_t)rowBase * 63 + g];
            const int row = g / 63;
            const int cc = g - row * 63;
            tile[row * ROW_OUT + cc] = val;
        }
        __syncthreads();
        const int total = rem * NPAIRS;
        for (int idx = t; idx < total; idx += NTHREADS) {
            const int row = idx / NPAIRS;
            const int p = idx - row * NPAIRS;
            const unsigned int c = CODES.c[p];
            const float* __restrict__ rp = tile + row * ROW_OUT;
            const int ca = (int)(c & 0xffffu);
            const int cb = (int)(c >> 16);
            const float dx = rp[ca] - rp[cb];
            const float dy = rp[ca + 1] - rp[cb + 1];
            tile[row * ROW_OUT + 63 + p] = __builtin_amdgcn_sqrtf(dx * dx + dy * dy);
        }
        __syncthreads();
        const int nout = rem * ROW_OUT;
        for (int k = t; k < nout; k += NTHREADS) {
            out[(size_t)rowBase * ROW_OUT + k] = tile[k];
        }
    }
}

extern "C" void kernel_launch(void* const* d_in, const int* in_sizes, int n_in,
                              void* d_out, int out_size, void* d_ws, size_t ws_size,
                              hipStream_t stream) {
    const float* in = (const float*)d_in[0];
    float* out = (float*)d_out;
    const int B = in_sizes[0] / 63;
    hipLaunchKernelGGL(HandKineticLayer_18545668784560_kernel,
                       dim3(GRID), dim3(NTHREADS), 0, stream,
                       in, out, B);
}